// Round 9
// baseline (300.574 us; speedup 1.0000x reference)
//
#include <hip/hip_runtime.h>

#define BATCH 131072
#define SN 32
#define H1 10
#define H2 6
#define ROWS 128                           // rows per block; lane pairs (lane, lane+64)
#define GRID (BATCH / ROWS)                // 1024 blocks = 4/CU exactly -> ALL co-resident
#define TPB 512                            // 8 waves/block -> 32 waves/CU
#define LDS_STRIDE 33                      // bank = (row + s) % 32 -> 2-way (free)

#define FB 2048                            // k_finish blocks
#define FT 256                             // k_finish threads

typedef float v2f __attribute__((ext_vector_type(2)));

__device__ __forceinline__ v2f bc(float s) { v2f r; r.x = s; r.y = s; return r; }
__device__ __forceinline__ v2f fma2(v2f a, v2f b, v2f c) {
    return __builtin_elementwise_fma(a, b, c);   // -> v_pk_fma_f32
}
__device__ __forceinline__ float fexp2(float x) {
#if __has_builtin(__builtin_amdgcn_exp2f)
    return __builtin_amdgcn_exp2f(x);            // v_exp_f32 (2^x)
#else
    return __expf(0.6931471805599453f * x);
#endif
}
// tanh(x) = 1 - 2/(2^(x*2log2e)+1): scale folded into ONE pk mul (was add+2mul)
__device__ __forceinline__ v2f tanh2(v2f x) {
    v2f xl = x * bc(2.885390081777927f);         // 2*log2(e)
    v2f e; e.x = fexp2(xl.x); e.y = fexp2(xl.y);
    v2f e1 = e + bc(1.0f);
    v2f r; r.x = __builtin_amdgcn_rcpf(e1.x); r.y = __builtin_amdgcn_rcpf(e1.y);
    return fma2(bc(-2.0f), r, bc(1.0f));
}

// DPP wave64 sum; total lands in lane 63. VALU-pipe only.
__device__ __forceinline__ float wave_sum(float v) {
    v += __int_as_float(__builtin_amdgcn_update_dpp(
            0, __float_as_int(v), 0x111, 0xf, 0xf, false));   // row_shr:1
    v += __int_as_float(__builtin_amdgcn_update_dpp(
            0, __float_as_int(v), 0x112, 0xf, 0xf, false));   // row_shr:2
    v += __int_as_float(__builtin_amdgcn_update_dpp(
            0, __float_as_int(v), 0x114, 0xf, 0xf, false));   // row_shr:4
    v += __int_as_float(__builtin_amdgcn_update_dpp(
            0, __float_as_int(v), 0x118, 0xf, 0xf, false));   // row_shr:8
    v += __int_as_float(__builtin_amdgcn_update_dpp(
            0, __float_as_int(v), 0x142, 0xa, 0xf, false));   // row_bcast:15
    v += __int_as_float(__builtin_amdgcn_update_dpp(
            0, __float_as_int(v), 0x143, 0xc, 0xf, false));   // row_bcast:31
    return v;
}

// ---------------- k_main: round-0 math + last-block reduction tail ----------
// R8 lesson: redundant per-block re-reads of partial are L3-bound (~201 MB,
// ~30us). Here exactly ONE block (the last to finish, via integer atomic
// counter) reduces partial -> acc[96] as a ~2us tail. Poison-proof: block 0
// zeroes cnt as its FIRST instruction; all 1024 blocks are co-resident
// (4/CU exactly), so this precedes every end-of-kernel increment by ~40us
// of compute regardless of ws fill pattern. No FP atomics (CAS-loop risk),
// no cooperative API (R4-R7 crash correlation).
__global__ __launch_bounds__(TPB) void k_main(
    const float* __restrict__ x,
    const float* __restrict__ W1, const float* __restrict__ B1,
    const float* __restrict__ W2, const float* __restrict__ B2,
    const float* __restrict__ W3, const float* __restrict__ B3,
    float* __restrict__ out, float* __restrict__ partial /* [3*SN][GRID] */,
    double* __restrict__ acc /* [3*SN] */, unsigned* __restrict__ cnt)
{
    __shared__ float xt[ROWS * LDS_STRIDE];   // 16.9 KB (x tile, then raw outputs)
    __shared__ unsigned lastflag;
    const int tid = threadIdx.x;
    const int lane = tid & 63;
    const int wave = tid >> 6;                // 0..7
    const int blk = blockIdx.x;

    if (blk == 0 && tid == 0) atomicExch(cnt, 0u);   // poison-proof reset

    // stage 128x32 x-tile coalesced, transpose-pad into LDS (2 float4/thread)
    const float4* xv = (const float4*)(x + (size_t)blk * ROWS * SN);
    #pragma unroll
    for (int it = 0; it < 2; ++it) {
        int v = it * TPB + tid;
        float4 val = xv[v];
        int r = v >> 3;                       // 8 float4 per row
        int c = (v & 7) << 2;
        float* dst = &xt[r * LDS_STRIDE + c];
        dst[0] = val.x; dst[1] = val.y; dst[2] = val.z; dst[3] = val.w;
    }
    __syncthreads();

    #pragma unroll 1
    for (int si = 0; si < 4; ++si) {
        // wave-uniform subnet id -> params land in SGPRs via s_load
        const int s = __builtin_amdgcn_readfirstlane(si * 8 + wave);
        const float* w1p = W1 + s * H1;
        const float* b1p = B1 + s * H1;
        const float* w2p = W2 + s * H1 * H2;
        const float* b2p = B2 + s * H2;
        const float* w3p = W3 + s * H2;
        const float b3 = B3[s];

        float w1r[H1], b1r[H1];
        #pragma unroll
        for (int i = 0; i < H1; ++i) { w1r[i] = w1p[i]; b1r[i] = b1p[i]; }
        float w2r[H1 * H2];
        #pragma unroll
        for (int k = 0; k < H1 * H2; ++k) w2r[k] = w2p[k];
        float b2r[H2], w3r[H2];
        #pragma unroll
        for (int j = 0; j < H2; ++j) { b2r[j] = b2p[j]; w3r[j] = w3p[j]; }

        v2f xs;
        xs.x = xt[lane * LDS_STRIDE + s];
        xs.y = xt[(lane + 64) * LDS_STRIDE + s];

        // layer 1: t = tanh(x w1 + b1); p = (1-t^2) w1; q' = t (1-t^2) w1^2
        v2f t[H1], p[H1], q[H1];
        #pragma unroll
        for (int i = 0; i < H1; ++i) {
            v2f u = fma2(xs, bc(w1r[i]), bc(b1r[i]));
            v2f ti = tanh2(u);
            v2f e = fma2(-ti, ti, bc(1.0f));
            t[i] = ti;
            p[i] = e * bc(w1r[i]);
            q[i] = (ti * p[i]) * bc(w1r[i]);
        }

        v2f o = bc(b3), g2a = bc(0.0f);
        #pragma unroll
        for (int j = 0; j < H2; ++j) {
            v2f vv = bc(b2r[j]), a = bc(0.0f), c = bc(0.0f);
            #pragma unroll
            for (int i = 0; i < H1; ++i) {
                v2f wb = bc(w2r[i * H2 + j]);
                vv = fma2(wb, t[i], vv);
                a  = fma2(wb, p[i], a);
                c  = fma2(wb, q[i], c);
            }
            v2f sj = tanh2(vv);
            v2f dj = fma2(-sj, sj, bc(1.0f));            // 1 - s^2
            v2f aa = a * a;
            v2f h  = fma2(sj, aa, c);                    // c' + s a^2
            v2f k  = dj * h;                             // g2_j = -2 k
            o   = fma2(bc(w3r[j]), sj, o);
            g2a = fma2(bc(w3r[j]), k, g2a);              // g2_true = -2 g2a
        }

        // raw outputs overwrite the just-consumed xt column (same wave)
        xt[lane * LDS_STRIDE + s] = o.x;
        xt[(lane + 64) * LDS_STRIDE + s] = o.y;

        v2f s2v = o * o;
        v2f s3v = (g2a * g2a) * bc(4.0f);                // (-2 g2a)^2
        float s1 = wave_sum(o.x + o.y);
        float s2 = wave_sum(s2v.x + s2v.y);
        float s3 = wave_sum(s3v.x + s3v.y);
        if (lane == 63) {
            partial[(size_t)(0 * SN + s) * GRID + blk] = s1;
            partial[(size_t)(1 * SN + s) * GRID + blk] = s2;
            partial[(size_t)(2 * SN + s) * GRID + blk] = s3;
        }
    }
    __syncthreads();

    // coalesced raw-output store
    float4* po = (float4*)out;
    const size_t base = (size_t)blk * (ROWS * SN / 4);
    #pragma unroll
    for (int it = 0; it < 2; ++it) {
        int v = it * TPB + tid;
        int r = v >> 3;
        int c = (v & 7) << 2;
        const float* src = &xt[r * LDS_STRIDE + c];
        float4 w; w.x = src[0]; w.y = src[1]; w.z = src[2]; w.w = src[3];
        po[base + v] = w;
    }

    // ---- last-block reduction: partial[96][1024] -> acc[96] (double) ----
    __threadfence();                          // release this block's partial writes
    if (tid == 0) {
        unsigned old = atomicAdd(cnt, 1u);
        lastflag = (old == GRID - 1) ? 1u : 0u;
    }
    __syncthreads();
    if (lastflag) {
        __threadfence();                      // acquire: see all blocks' partials
        for (int r = wave; r < 3 * SN; r += 8) {
            const float4* pr = (const float4*)(partial + (size_t)r * GRID);
            double sd = 0.0;
            #pragma unroll
            for (int k2 = 0; k2 < 4; ++k2) {
                float4 v4 = pr[k2 * 64 + lane];           // coalesced
                sd += (double)v4.x + (double)v4.y + (double)v4.z + (double)v4.w;
            }
            #pragma unroll
            for (int off = 32; off > 0; off >>= 1) sd += __shfl_down(sd, off);
            if (lane == 0) acc[r] = sd;
        }
    }
}

// ---------------- k_finish: stats from acc (768 B) + normalize stream ------
__global__ __launch_bounds__(FT) void k_finish(float* __restrict__ out,
                                               const double* __restrict__ acc)
{
    __shared__ float mean_s[SN], inv_s[SN];
    const int tid = threadIdx.x;
    const double invB = 1.0 / (double)BATCH;

    if (tid < SN) {
        double mean = acc[tid] * invB;
        double var = acc[SN + tid] * invB - mean * mean;
        if (var < 0.0) var = 0.0;
        mean_s[tid] = (float)mean;
        inv_s[tid] = (float)(1.0 / sqrt(var + 1e-10));
    }
    if (blockIdx.x == 0 && tid < 64) {
        double term = 0.0;
        if (tid < SN) {
            double mean = acc[tid] * invB;
            double var = acc[SN + tid] * invB - mean * mean;
            if (var < 0.0) var = 0.0;
            term = (acc[2 * SN + tid] * invB) / sqrt(var);   // no eps (matches ref)
        }
        #pragma unroll
        for (int off = 16; off > 0; off >>= 1) term += __shfl_down(term, off);
        if (tid == 0) out[(size_t)BATCH * SN] = (float)(0.001 * term);
    }
    __syncthreads();

    // grid-stride normalize: 1,048,576 float4 over 2048x256 threads = 2/thread
    float4* p = (float4*)out;
    const int total = BATCH * SN / 4;
    for (int v = blockIdx.x * FT + tid; v < total; v += FB * FT) {
        float4 val = p[v];
        const int c = (v & 7) << 2;                       // subnet base
        val.x = (val.x - mean_s[c + 0]) * inv_s[c + 0];
        val.y = (val.y - mean_s[c + 1]) * inv_s[c + 1];
        val.z = (val.z - mean_s[c + 2]) * inv_s[c + 2];
        val.w = (val.w - mean_s[c + 3]) * inv_s[c + 3];
        p[v] = val;
    }
}

extern "C" void kernel_launch(void* const* d_in, const int* in_sizes, int n_in,
                              void* d_out, int out_size, void* d_ws, size_t ws_size,
                              hipStream_t stream) {
    const float* x  = (const float*)d_in[0];
    const float* W1 = (const float*)d_in[1];
    const float* B1 = (const float*)d_in[2];
    const float* W2 = (const float*)d_in[3];
    const float* B2 = (const float*)d_in[4];
    const float* W3 = (const float*)d_in[5];
    const float* B3 = (const float*)d_in[6];

    float* out = (float*)d_out;                 // [BATCH*SN] out_bn, then [1] loss
    // ws layout: partial [96][1024] f32 (393216 B) | acc [96] f64 | cnt u32
    float* partial = (float*)d_ws;
    double* acc = (double*)((char*)d_ws + (size_t)3 * SN * GRID * sizeof(float));
    unsigned* cnt = (unsigned*)((char*)acc + 3 * SN * sizeof(double));

    k_main<<<GRID, TPB, 0, stream>>>(x, W1, B1, W2, B2, W3, B3, out, partial,
                                     acc, cnt);
    k_finish<<<FB, FT, 0, stream>>>(out, acc);
}

// Round 10
// 130.901 us; speedup vs baseline: 2.2962x; 2.2962x over previous
//
#include <hip/hip_runtime.h>

#define BATCH 131072
#define SN 32
#define H1 10
#define H2 6
#define ROWS 128                           // rows per block; lane pairs (lane, lane+64)
#define GRID (BATCH / ROWS)                // 1024
#define TPB 512                            // 8 waves/block -> 32 waves/CU at 4 blocks/CU
#define LDS_STRIDE 33                      // bank = (row + s) % 32 -> 2-way (free)

#define FB 2048                            // k_finish blocks = 8/CU exactly (co-resident)
#define FT 256                             // k_finish threads

typedef float v2f __attribute__((ext_vector_type(2)));

__device__ __forceinline__ v2f bc(float s) { v2f r; r.x = s; r.y = s; return r; }
__device__ __forceinline__ v2f fma2(v2f a, v2f b, v2f c) {
    return __builtin_elementwise_fma(a, b, c);   // -> v_pk_fma_f32
}
__device__ __forceinline__ float fexp2(float x) {
#if __has_builtin(__builtin_amdgcn_exp2f)
    return __builtin_amdgcn_exp2f(x);            // v_exp_f32 (2^x)
#else
    return __expf(0.6931471805599453f * x);
#endif
}
// tanh(x) = 1 - 2/(2^(x*2log2e)+1): scale folded into ONE pk mul
__device__ __forceinline__ v2f tanh2(v2f x) {
    v2f xl = x * bc(2.885390081777927f);         // 2*log2(e)
    v2f e; e.x = fexp2(xl.x); e.y = fexp2(xl.y);
    v2f e1 = e + bc(1.0f);
    v2f r; r.x = __builtin_amdgcn_rcpf(e1.x); r.y = __builtin_amdgcn_rcpf(e1.y);
    return fma2(bc(-2.0f), r, bc(1.0f));
}

// DPP wave64 sum; total lands in lane 63. VALU-pipe only.
__device__ __forceinline__ float wave_sum(float v) {
    v += __int_as_float(__builtin_amdgcn_update_dpp(
            0, __float_as_int(v), 0x111, 0xf, 0xf, false));   // row_shr:1
    v += __int_as_float(__builtin_amdgcn_update_dpp(
            0, __float_as_int(v), 0x112, 0xf, 0xf, false));   // row_shr:2
    v += __int_as_float(__builtin_amdgcn_update_dpp(
            0, __float_as_int(v), 0x114, 0xf, 0xf, false));   // row_shr:4
    v += __int_as_float(__builtin_amdgcn_update_dpp(
            0, __float_as_int(v), 0x118, 0xf, 0xf, false));   // row_shr:8
    v += __int_as_float(__builtin_amdgcn_update_dpp(
            0, __float_as_int(v), 0x142, 0xa, 0xf, false));   // row_bcast:15
    v += __int_as_float(__builtin_amdgcn_update_dpp(
            0, __float_as_int(v), 0x143, 0xc, 0xf, false));   // row_bcast:31
    return v;
}

// ---------------- k_main: R0-proven body (43.8us), exp2-folded tanh --------
// R9 lesson: per-block __threadfence() (agent fence -> L2 writeback) x1024
// serialized ~190us of stall (VALUBusy 63%->11.5%, same busy-time). No
// fences, no atomics here; cross-kernel visibility of partial/out comes free
// from the end-of-kernel flush + stream order. Block 0 resets the k_finish
// flag (stream-ordered: k_finish starts only after k_main fully completes).
__global__ __launch_bounds__(TPB) void k_main(
    const float* __restrict__ x,
    const float* __restrict__ W1, const float* __restrict__ B1,
    const float* __restrict__ W2, const float* __restrict__ B2,
    const float* __restrict__ W3, const float* __restrict__ B3,
    float* __restrict__ out, float* __restrict__ partial /* [3*SN][GRID] */,
    unsigned* __restrict__ flag)
{
    __shared__ float xt[ROWS * LDS_STRIDE];   // 16.9 KB (x tile, then raw outputs)
    const int tid = threadIdx.x;
    const int lane = tid & 63;
    const int wave = tid >> 6;                // 0..7
    const int blk = blockIdx.x;

    if (blk == 0 && tid == 0)
        __hip_atomic_store(flag, 0u, __ATOMIC_RELAXED, __HIP_MEMORY_SCOPE_AGENT);

    // stage 128x32 x-tile coalesced, transpose-pad into LDS (2 float4/thread)
    const float4* xv = (const float4*)(x + (size_t)blk * ROWS * SN);
    #pragma unroll
    for (int it = 0; it < 2; ++it) {
        int v = it * TPB + tid;
        float4 val = xv[v];
        int r = v >> 3;                       // 8 float4 per row
        int c = (v & 7) << 2;
        float* dst = &xt[r * LDS_STRIDE + c];
        dst[0] = val.x; dst[1] = val.y; dst[2] = val.z; dst[3] = val.w;
    }
    __syncthreads();

    #pragma unroll 1
    for (int si = 0; si < 4; ++si) {
        // wave-uniform subnet id -> params land in SGPRs via s_load
        const int s = __builtin_amdgcn_readfirstlane(si * 8 + wave);
        const float* w1p = W1 + s * H1;
        const float* b1p = B1 + s * H1;
        const float* w2p = W2 + s * H1 * H2;
        const float* b2p = B2 + s * H2;
        const float* w3p = W3 + s * H2;
        const float b3 = B3[s];

        float w1r[H1], b1r[H1];
        #pragma unroll
        for (int i = 0; i < H1; ++i) { w1r[i] = w1p[i]; b1r[i] = b1p[i]; }
        float w2r[H1 * H2];
        #pragma unroll
        for (int k = 0; k < H1 * H2; ++k) w2r[k] = w2p[k];
        float b2r[H2], w3r[H2];
        #pragma unroll
        for (int j = 0; j < H2; ++j) { b2r[j] = b2p[j]; w3r[j] = w3p[j]; }

        v2f xs;
        xs.x = xt[lane * LDS_STRIDE + s];
        xs.y = xt[(lane + 64) * LDS_STRIDE + s];

        // layer 1: t = tanh(x w1 + b1); p = (1-t^2) w1; q' = t (1-t^2) w1^2
        v2f t[H1], p[H1], q[H1];
        #pragma unroll
        for (int i = 0; i < H1; ++i) {
            v2f u = fma2(xs, bc(w1r[i]), bc(b1r[i]));
            v2f ti = tanh2(u);
            v2f e = fma2(-ti, ti, bc(1.0f));
            t[i] = ti;
            p[i] = e * bc(w1r[i]);
            q[i] = (ti * p[i]) * bc(w1r[i]);
        }

        v2f o = bc(b3), g2a = bc(0.0f);
        #pragma unroll
        for (int j = 0; j < H2; ++j) {
            v2f vv = bc(b2r[j]), a = bc(0.0f), c = bc(0.0f);
            #pragma unroll
            for (int i = 0; i < H1; ++i) {
                v2f wb = bc(w2r[i * H2 + j]);
                vv = fma2(wb, t[i], vv);
                a  = fma2(wb, p[i], a);
                c  = fma2(wb, q[i], c);
            }
            v2f sj = tanh2(vv);
            v2f dj = fma2(-sj, sj, bc(1.0f));            // 1 - s^2
            v2f aa = a * a;
            v2f h  = fma2(sj, aa, c);                    // c' + s a^2
            v2f k  = dj * h;                             // g2_j = -2 k
            o   = fma2(bc(w3r[j]), sj, o);
            g2a = fma2(bc(w3r[j]), k, g2a);              // g2_true = -2 g2a
        }

        // raw outputs overwrite the just-consumed xt column (same wave)
        xt[lane * LDS_STRIDE + s] = o.x;
        xt[(lane + 64) * LDS_STRIDE + s] = o.y;

        v2f s2v = o * o;
        v2f s3v = (g2a * g2a) * bc(4.0f);                // (-2 g2a)^2
        float s1 = wave_sum(o.x + o.y);
        float s2 = wave_sum(s2v.x + s2v.y);
        float s3 = wave_sum(s3v.x + s3v.y);
        if (lane == 63) {
            partial[(size_t)(0 * SN + s) * GRID + blk] = s1;
            partial[(size_t)(1 * SN + s) * GRID + blk] = s2;
            partial[(size_t)(2 * SN + s) * GRID + blk] = s3;
        }
    }
    __syncthreads();

    // coalesced raw-output store
    float4* po = (float4*)out;
    const size_t base = (size_t)blk * (ROWS * SN / 4);
    #pragma unroll
    for (int it = 0; it < 2; ++it) {
        int v = it * TPB + tid;
        int r = v >> 3;
        int c = (v & 7) << 2;
        const float* src = &xt[r * LDS_STRIDE + c];
        float4 w; w.x = src[0]; w.y = src[1]; w.z = src[2]; w.w = src[3];
        po[base + v] = w;
    }
}

// ---------------- k_finish: single-producer reduce + spin + normalize -------
// 2048 blocks x 256 thr = 8 blocks/CU exactly -> block 0 (dispatched first)
// is always resident -> no deadlock; late blocks see flag already set.
// Exactly ONE agent-scope release in the whole grid (block 0's flag store);
// consumers use relaxed agent loads (go to coherence point, no invalidates).
__global__ __launch_bounds__(FT) void k_finish(
    float* __restrict__ out, const float* __restrict__ partial,
    float* __restrict__ stats /* [2*SN] */, unsigned* __restrict__ flag)
{
    __shared__ float mean_s[SN], inv_s[SN];
    const int tid = threadIdx.x;
    const int lane = tid & 63;
    const int wave = tid >> 6;                // 0..3
    const double invB = 1.0 / (double)BATCH;

    if (blockIdx.x == 0) {
        // ---- producer: reduce partial[96][1024] -> stats ----
        __shared__ double red_s[3 * SN];
        for (int r = wave; r < 3 * SN; r += 4) {
            const float4* pr = (const float4*)(partial + (size_t)r * GRID);
            double sd = 0.0;
            #pragma unroll
            for (int k = 0; k < 4; ++k) {
                float4 v4 = pr[k * 64 + lane];    // coalesced
                sd += (double)v4.x + (double)v4.y + (double)v4.z + (double)v4.w;
            }
            #pragma unroll
            for (int off = 32; off > 0; off >>= 1) sd += __shfl_down(sd, off);
            if (lane == 0) red_s[r] = sd;
        }
        __syncthreads();

        if (tid < SN) {
            double mean = red_s[tid] * invB;
            double var = red_s[SN + tid] * invB - mean * mean;
            if (var < 0.0) var = 0.0;
            float m = (float)mean;
            float iv = (float)(1.0 / sqrt(var + 1e-10));
            mean_s[tid] = m;
            inv_s[tid] = iv;
            __hip_atomic_store(&stats[tid], m, __ATOMIC_RELAXED,
                               __HIP_MEMORY_SCOPE_AGENT);
            __hip_atomic_store(&stats[SN + tid], iv, __ATOMIC_RELAXED,
                               __HIP_MEMORY_SCOPE_AGENT);
        }
        if (tid < 64) {
            double term = 0.0;
            if (tid < SN) {
                double mean = red_s[tid] * invB;
                double var = red_s[SN + tid] * invB - mean * mean;
                if (var < 0.0) var = 0.0;
                term = (red_s[2 * SN + tid] * invB) / sqrt(var);  // no eps (ref)
            }
            #pragma unroll
            for (int off = 16; off > 0; off >>= 1) term += __shfl_down(term, off);
            if (tid == 0) out[(size_t)BATCH * SN] = (float)(0.001 * term);
        }
        __syncthreads();
        if (tid == 0)      // the ONE release (single L2 writeback grid-wide)
            __hip_atomic_store(flag, 1u, __ATOMIC_RELEASE,
                               __HIP_MEMORY_SCOPE_AGENT);
    } else {
        // ---- consumers: sleep-spin on flag, then pull stats from L3 ----
        if (tid == 0) {
            while (__hip_atomic_load(flag, __ATOMIC_RELAXED,
                                     __HIP_MEMORY_SCOPE_AGENT) == 0u)
                __builtin_amdgcn_s_sleep(2);
        }
        __syncthreads();
        if (tid < 2 * SN) {
            float v = __hip_atomic_load(&stats[tid], __ATOMIC_RELAXED,
                                        __HIP_MEMORY_SCOPE_AGENT);
            if (tid < SN) mean_s[tid] = v; else inv_s[tid - SN] = v;
        }
        __syncthreads();
    }

    // ---- grid-stride normalize: 1,048,576 float4 / (2048x256) = 2/thread --
    float4* p = (float4*)out;
    const int total = BATCH * SN / 4;
    for (int v = blockIdx.x * FT + tid; v < total; v += FB * FT) {
        float4 val = p[v];
        const int c = (v & 7) << 2;                       // subnet base
        val.x = (val.x - mean_s[c + 0]) * inv_s[c + 0];
        val.y = (val.y - mean_s[c + 1]) * inv_s[c + 1];
        val.z = (val.z - mean_s[c + 2]) * inv_s[c + 2];
        val.w = (val.w - mean_s[c + 3]) * inv_s[c + 3];
        p[v] = val;
    }
}

extern "C" void kernel_launch(void* const* d_in, const int* in_sizes, int n_in,
                              void* d_out, int out_size, void* d_ws, size_t ws_size,
                              hipStream_t stream) {
    const float* x  = (const float*)d_in[0];
    const float* W1 = (const float*)d_in[1];
    const float* B1 = (const float*)d_in[2];
    const float* W2 = (const float*)d_in[3];
    const float* B2 = (const float*)d_in[4];
    const float* W3 = (const float*)d_in[5];
    const float* B3 = (const float*)d_in[6];

    float* out = (float*)d_out;                 // [BATCH*SN] out_bn, then [1] loss
    // ws: partial [96][1024] f32 (393216 B) | stats [64] f32 | flag u32
    float* partial = (float*)d_ws;
    float* stats = (float*)((char*)d_ws + (size_t)3 * SN * GRID * sizeof(float));
    unsigned* flag = (unsigned*)((char*)stats + 2 * SN * sizeof(float));

    k_main<<<GRID, TPB, 0, stream>>>(x, W1, B1, W2, B2, W3, B3, out, partial,
                                     flag);
    k_finish<<<FB, FT, 0, stream>>>(out, partial, stats, flag);
}